// Round 1
// baseline (959.412 us; speedup 1.0000x reference)
//
#include <hip/hip_runtime.h>
#include <hip/hip_bf16.h>

// Problem constants (derived from harness sizes at launch where possible)
// ATOM_DIMS = [119,5,12,12,10,6,6,2,2] -> offsets below, 174 embedding rows.
// H=64, NH=8, DH=8. Layout note: reshape(N, DH, NH) of row-major [N,64]
// means element [n,d,h] = flat[n*64 + d*8 + h]  (head index fastest).

#define NPB 4  // nodes (or edges) per 256-thread block: one 64-lane wave each

__global__ void encode_qkv_kernel(const int* __restrict__ X,
                                  const float* __restrict__ atom_emb,
                                  const float* __restrict__ Wq, const float* __restrict__ bq,
                                  const float* __restrict__ Wk, const float* __restrict__ bk,
                                  const float* __restrict__ Wv, const float* __restrict__ bv,
                                  float* __restrict__ q, float* __restrict__ k,
                                  float* __restrict__ v, int N)
{
    __shared__ float sWq[64 * 64];
    __shared__ float sWk[64 * 64];
    __shared__ float sWv[64 * 64];
    __shared__ float sh[NPB][64];

    const int tid = threadIdx.x;
    for (int i = tid; i < 64 * 64; i += 256) {
        sWq[i] = Wq[i];
        sWk[i] = Wk[i];
        sWv[i] = Wv[i];
    }

    const int g = tid >> 6;
    const int lane = tid & 63;
    const int n = blockIdx.x * NPB + g;

    if (n < N) {
        const int offs[9] = {0, 119, 124, 136, 148, 158, 164, 170, 172};
        float hval = 0.f;
#pragma unroll
        for (int f = 0; f < 9; ++f) {
            int idx = X[n * 9 + f] + offs[f];
            hval += atom_emb[idx * 64 + lane];
        }
        sh[g][lane] = hval;  // written & read by the same wave; block sync below
    }
    __syncthreads();  // covers the sW* staging

    if (n < N) {
        float accq = bq[lane], acck = bk[lane], accv = bv[lane];
#pragma unroll
        for (int i = 0; i < 64; ++i) {
            float hv = sh[g][i];
            accq = fmaf(hv, sWq[i * 64 + lane], accq);
            acck = fmaf(hv, sWk[i * 64 + lane], acck);
            accv = fmaf(hv, sWv[i * 64 + lane], accv);
        }
        const float scaling = 0.35355339059327373f;  // DH^-0.5 = 8^-0.5
        q[n * 64 + lane] = accq * scaling;
        k[n * 64 + lane] = acck;
        v[n * 64 + lane] = accv;
    }
}

// score[e,h] = sum_d q[row_e, d*8+h] * k[col_e, d*8+h]; atomicMax running max per (row,h)
__global__ void sddmm_kernel(const int* __restrict__ row, const int* __restrict__ col,
                             const float* __restrict__ q, const float* __restrict__ k,
                             float* __restrict__ score, unsigned int* __restrict__ mkey,
                             int E)
{
    const int tid = threadIdx.x;
    const int g = tid >> 6;
    const int lane = tid & 63;
    const int e = blockIdx.x * NPB + g;
    if (e >= E) return;

    const int r = row[e];
    const int c = col[e];
    float prod = q[r * 64 + lane] * k[c * 64 + lane];
    // reduce over d (lane bits 3..5), keep per-head (lane bits 0..2)
    prod += __shfl_xor(prod, 8, 64);
    prod += __shfl_xor(prod, 16, 64);
    prod += __shfl_xor(prod, 32, 64);

    if (lane < 8) {
        score[e * 8 + lane] = prod;
        unsigned int bits = __float_as_uint(prod);
        // monotone float->uint key; key(x) increasing in x; 0 == "-inf" identity
        unsigned int key = (bits & 0x80000000u) ? ~bits : (bits | 0x80000000u);
        atomicMax(&mkey[r * 8 + lane], key);
    }
}

// p = exp(score - m[row]); ssum[row,h] += p; tmp[row, d*8+h] += p * v[col, d*8+h]
__global__ void spmm_kernel(const int* __restrict__ row, const int* __restrict__ col,
                            const float* __restrict__ v, const float* __restrict__ score,
                            const unsigned int* __restrict__ mkey,
                            float* __restrict__ ssum, float* __restrict__ tmp, int E)
{
    const int tid = threadIdx.x;
    const int g = tid >> 6;
    const int lane = tid & 63;
    const int e = blockIdx.x * NPB + g;
    if (e >= E) return;

    const int r = row[e];
    const int c = col[e];
    const int h = lane & 7;

    unsigned int key = mkey[r * 8 + h];
    unsigned int mbits = (key & 0x80000000u) ? (key ^ 0x80000000u) : ~key;
    float m = __uint_as_float(mbits);
    float s = score[e * 8 + h];
    float p = __expf(s - m);  // s <= m, so p in (0,1]

    if (lane < 8) unsafeAtomicAdd(&ssum[r * 8 + lane], p);
    float val = p * v[c * 64 + lane];
    unsafeAtomicAdd(&tmp[r * 64 + lane], val);
}

// out[n,j] = bo[j] + sum_i (tmp[n,i]/ssum[n, i&7]) * Wo[i,j]; empty segments -> 0
__global__ void out_proj_kernel(const float* __restrict__ tmp, const float* __restrict__ ssum,
                                const float* __restrict__ Wo, const float* __restrict__ bo,
                                float* __restrict__ out, int N)
{
    __shared__ float sWo[64 * 64];
    __shared__ float sh[NPB][64];

    const int tid = threadIdx.x;
    for (int i = tid; i < 64 * 64; i += 256) sWo[i] = Wo[i];

    const int g = tid >> 6;
    const int lane = tid & 63;
    const int n = blockIdx.x * NPB + g;

    if (n < N) {
        float denom = ssum[n * 8 + (lane & 7)];
        float t = tmp[n * 64 + lane];
        sh[g][lane] = denom > 0.f ? t / denom : 0.f;
    }
    __syncthreads();  // covers sWo staging (sh is wave-local)

    if (n < N) {
        float acc = bo[lane];
#pragma unroll
        for (int i = 0; i < 64; ++i) acc = fmaf(sh[g][i], sWo[i * 64 + lane], acc);
        out[n * 64 + lane] = acc;
    }
}

extern "C" void kernel_launch(void* const* d_in, const int* in_sizes, int n_in,
                              void* d_out, int out_size, void* d_ws, size_t ws_size,
                              hipStream_t stream)
{
    const int*   X        = (const int*)d_in[0];
    const int*   row      = (const int*)d_in[1];
    const int*   col      = (const int*)d_in[2];
    const float* atom_emb = (const float*)d_in[3];
    const float* Wq       = (const float*)d_in[4];
    const float* bq       = (const float*)d_in[5];
    const float* Wk       = (const float*)d_in[6];
    const float* bk       = (const float*)d_in[7];
    const float* Wv       = (const float*)d_in[8];
    const float* bv       = (const float*)d_in[9];
    const float* Wo       = (const float*)d_in[10];
    const float* bo       = (const float*)d_in[11];

    const int N = in_sizes[0] / 9;
    const int E = in_sizes[1];

    // Workspace layout (floats): q | k | v | score | mkey | ssum | tmp
    float* ws    = (float*)d_ws;
    float* q     = ws;
    float* k     = q + (size_t)N * 64;
    float* v     = k + (size_t)N * 64;
    float* score = v + (size_t)N * 64;
    unsigned int* mkey = (unsigned int*)(score + (size_t)E * 8);
    float* ssum  = (float*)(mkey + (size_t)N * 8);
    float* tmp   = ssum + (size_t)N * 8;
    // total = N*64*3 + E*8 + N*8*2 + N*64 floats  (~160 MB at N=100K, E=1.6M)

    // Zero the atomically-accumulated regions: mkey, ssum, tmp (contiguous)
    size_t zero_bytes = ((size_t)N * 8 + (size_t)N * 8 + (size_t)N * 64) * sizeof(float);
    hipMemsetAsync(mkey, 0, zero_bytes, stream);

    encode_qkv_kernel<<<(N + NPB - 1) / NPB, 256, 0, stream>>>(
        X, atom_emb, Wq, bq, Wk, bk, Wv, bv, q, k, v, N);

    sddmm_kernel<<<(E + NPB - 1) / NPB, 256, 0, stream>>>(row, col, q, k, score, mkey, E);

    spmm_kernel<<<(E + NPB - 1) / NPB, 256, 0, stream>>>(row, col, v, score, mkey, ssum, tmp, E);

    out_proj_kernel<<<(N + NPB - 1) / NPB, 256, 0, stream>>>(tmp, ssum, Wo, bo, (float*)d_out, N);
}

// Round 3
// 645.230 us; speedup vs baseline: 1.4869x; 1.4869x over previous
//
#include <hip/hip_runtime.h>
#include <hip/hip_bf16.h>

// GTLayer: AtomEncoder -> QKV -> sparse MHA (SDDMM + segment softmax + SpMM) -> out proj
// H=64, NH=8, DH=8. reshape(N, DH, NH) of row-major [N,64] => [n,d,h] = flat[n*64 + d*8 + h].
//
// Round-3 structure: CSR by destination row (int atomics only), then ONE wave per
// node computes scores + ONLINE softmax + SpMM + normalize + out-proj in a single
// pass with register accumulation. No float atomics, no global score stash
// (round-2's global stash had a same-wave cross-lane L1 visibility hazard).

#define NPB 4  // waves (nodes) per 256-thread block

// ---------------- encode: atom embedding sum + QKV projection ----------------
__global__ void encode_qkv_kernel(const int* __restrict__ X,
                                  const float* __restrict__ atom_emb,
                                  const float* __restrict__ Wq, const float* __restrict__ bq,
                                  const float* __restrict__ Wk, const float* __restrict__ bk,
                                  const float* __restrict__ Wv, const float* __restrict__ bv,
                                  float* __restrict__ q, float* __restrict__ k,
                                  float* __restrict__ v, int N)
{
    __shared__ float sWq[64 * 64];
    __shared__ float sWk[64 * 64];
    __shared__ float sWv[64 * 64];
    __shared__ float sh[NPB][64];

    const int tid = threadIdx.x;
    for (int i = tid; i < 64 * 64; i += 256) {
        sWq[i] = Wq[i];
        sWk[i] = Wk[i];
        sWv[i] = Wv[i];
    }

    const int g = tid >> 6;
    const int lane = tid & 63;
    const int n = blockIdx.x * NPB + g;

    if (n < N) {
        const int offs[9] = {0, 119, 124, 136, 148, 158, 164, 170, 172};
        float hval = 0.f;
#pragma unroll
        for (int f = 0; f < 9; ++f) {
            int idx = X[n * 9 + f] + offs[f];
            hval += atom_emb[idx * 64 + lane];
        }
        sh[g][lane] = hval;  // same-wave producer/consumer; barrier below covers sW*
    }
    __syncthreads();

    if (n < N) {
        float accq = bq[lane], acck = bk[lane], accv = bv[lane];
#pragma unroll
        for (int i = 0; i < 64; ++i) {
            float hv = sh[g][i];
            accq = fmaf(hv, sWq[i * 64 + lane], accq);
            acck = fmaf(hv, sWk[i * 64 + lane], acck);
            accv = fmaf(hv, sWv[i * 64 + lane], accv);
        }
        const float scaling = 0.35355339059327373f;  // 8^-0.5
        q[n * 64 + lane] = accq * scaling;
        k[n * 64 + lane] = acck;
        v[n * 64 + lane] = accv;
    }
}

// ---------------- CSR build ----------------
__global__ void degree_kernel(const int* __restrict__ row, int* __restrict__ deg, int E)
{
    int e = blockIdx.x * 256 + threadIdx.x;
    if (e < E) atomicAdd(&deg[row[e]], 1);
}

// per-1024-element tile exclusive scan; tile sums out
__global__ void scan_local_kernel(const int* __restrict__ deg, int* __restrict__ offs,
                                  int* __restrict__ tsum, int N)
{
    __shared__ int lds[256];
    const int t = threadIdx.x;
    const int tbase = blockIdx.x * 1024;

    int v0[4];
    int s = 0;
#pragma unroll
    for (int i = 0; i < 4; ++i) {
        int idx = tbase + t * 4 + i;
        v0[i] = (idx < N) ? deg[idx] : 0;
        s += v0[i];
    }
    lds[t] = s;
    __syncthreads();
    for (int off = 1; off < 256; off <<= 1) {
        int x = (t >= off) ? lds[t - off] : 0;
        __syncthreads();
        lds[t] += x;
        __syncthreads();
    }
    if (t == 255) tsum[blockIdx.x] = lds[255];
    int run = (t > 0) ? lds[t - 1] : 0;
#pragma unroll
    for (int i = 0; i < 4; ++i) {
        int idx = tbase + t * 4 + i;
        if (idx < N) offs[idx] = run;
        run += v0[i];
    }
}

// single-block exclusive scan of tile sums (nT <= 1024)
__global__ void scan_tsum_kernel(int* __restrict__ tsum, int nT)
{
    __shared__ int lds[1024];
    const int t = threadIdx.x;
    lds[t] = (t < nT) ? tsum[t] : 0;
    __syncthreads();
    for (int off = 1; off < 1024; off <<= 1) {
        int x = (t >= off) ? lds[t - off] : 0;
        __syncthreads();
        lds[t] += x;
        __syncthreads();
    }
    if (t < nT) tsum[t] = (t > 0) ? lds[t - 1] : 0;
}

__global__ void add_base_kernel(int* __restrict__ offs, const int* __restrict__ tsum,
                                int* __restrict__ cursor, int N)
{
    int i = blockIdx.x * 256 + threadIdx.x;
    if (i < N) {
        int o = offs[i] + tsum[i >> 10];
        offs[i] = o;
        cursor[i] = o;
    }
}

__global__ void scatter_kernel(const int* __restrict__ row, const int* __restrict__ col,
                               int* __restrict__ cursor, int* __restrict__ csr_col, int E)
{
    int e = blockIdx.x * 256 + threadIdx.x;
    if (e < E) {
        int pos = atomicAdd(&cursor[row[e]], 1);
        csr_col[pos] = col[e];
    }
}

// ---------------- fused per-node attention + out-proj (online softmax) ----------------
// One wave per node. For each incident edge: score via q.k shuffle-reduce (all
// lanes end with their head's score), then branchless online-softmax update of
// (m, sumP, acc) in registers. Normalize, LDS exchange, matvec with Wo.
__global__ void node_attn_kernel(const float* __restrict__ q, const float* __restrict__ k,
                                 const float* __restrict__ v,
                                 const int* __restrict__ offs, const int* __restrict__ deg,
                                 const int* __restrict__ csr_col,
                                 const float* __restrict__ Wo, const float* __restrict__ bo,
                                 float* __restrict__ out, int N)
{
    __shared__ float sWo[64 * 64];
    __shared__ float sh[NPB][64];

    const int tid = threadIdx.x;
    for (int i = tid; i < 64 * 64; i += 256) sWo[i] = Wo[i];

    const int g = tid >> 6;
    const int lane = tid & 63;
    const int n = blockIdx.x * NPB + g;

    if (n < N) {
        const int base = offs[n];
        const int d = deg[n];
        const float qreg = q[n * 64 + lane];

        float m = -3.4e38f;   // finite "-inf": first corr = exp(-3.4e38) = 0, no NaN
        float sumP = 0.f;
        float acc = 0.f;
        for (int j = 0; j < d; ++j) {
            int c = csr_col[base + j];
            float prod = qreg * k[c * 64 + lane];
            prod += __shfl_xor(prod, 8, 64);
            prod += __shfl_xor(prod, 16, 64);
            prod += __shfl_xor(prod, 32, 64);  // every lane: score for head lane&7

            float mNew = fmaxf(m, prod);
            float corr = __expf(m - mNew);     // 1 if max unchanged, else downscale
            float p = __expf(prod - mNew);
            sumP = fmaf(sumP, corr, p);
            acc  = fmaf(acc, corr, p * v[c * 64 + lane]);
            m = mNew;
        }
        sh[g][lane] = (d > 0) ? acc / sumP : 0.f;  // empty segment -> 0 -> out = bo
    }
    __syncthreads();  // covers sWo staging and sh writes

    if (n < N) {
        float o = bo[lane];
#pragma unroll
        for (int i = 0; i < 64; ++i) o = fmaf(sh[g][i], sWo[i * 64 + lane], o);
        out[n * 64 + lane] = o;
    }
}

extern "C" void kernel_launch(void* const* d_in, const int* in_sizes, int n_in,
                              void* d_out, int out_size, void* d_ws, size_t ws_size,
                              hipStream_t stream)
{
    const int*   X        = (const int*)d_in[0];
    const int*   row      = (const int*)d_in[1];
    const int*   col      = (const int*)d_in[2];
    const float* atom_emb = (const float*)d_in[3];
    const float* Wq       = (const float*)d_in[4];
    const float* bq       = (const float*)d_in[5];
    const float* Wk       = (const float*)d_in[6];
    const float* bk       = (const float*)d_in[7];
    const float* Wv       = (const float*)d_in[8];
    const float* bv       = (const float*)d_in[9];
    const float* Wo       = (const float*)d_in[10];
    const float* bo       = (const float*)d_in[11];

    const int N = in_sizes[0] / 9;
    const int E = in_sizes[1];
    const int nTiles = (N + 1023) / 1024;

    // Workspace layout: q | k | v | offs | deg | cursor | tsum | csr_col
    float* q   = (float*)d_ws;
    float* k   = q + (size_t)N * 64;
    float* v   = k + (size_t)N * 64;
    int* offs    = (int*)(v + (size_t)N * 64);       // N
    int* deg     = offs + N;                         // N
    int* cursor  = deg + N;                          // N
    int* tsum    = cursor + N;                       // nTiles (<=1024)
    int* csr_col = tsum + 1024;                      // E
    // total ~ (19.2M + 0.3M + 1.6M)*4B ~ 85 MB

    // ws is poisoned 0xAA before every timed call: zero the histogram.
    hipMemsetAsync(deg, 0, (size_t)N * sizeof(int), stream);

    encode_qkv_kernel<<<(N + NPB - 1) / NPB, 256, 0, stream>>>(
        X, atom_emb, Wq, bq, Wk, bk, Wv, bv, q, k, v, N);

    degree_kernel<<<(E + 255) / 256, 256, 0, stream>>>(row, deg, E);
    scan_local_kernel<<<nTiles, 256, 0, stream>>>(deg, offs, tsum, N);
    scan_tsum_kernel<<<1, 1024, 0, stream>>>(tsum, nTiles);
    add_base_kernel<<<(N + 255) / 256, 256, 0, stream>>>(offs, tsum, cursor, N);
    scatter_kernel<<<(E + 255) / 256, 256, 0, stream>>>(row, col, cursor, csr_col, E);

    node_attn_kernel<<<(N + NPB - 1) / NPB, 256, 0, stream>>>(
        q, k, v, offs, deg, csr_col, Wo, bo, (float*)d_out, N);
}

// Round 4
// 529.299 us; speedup vs baseline: 1.8126x; 1.2190x over previous
//
#include <hip/hip_runtime.h>
#include <hip/hip_bf16.h>

// GTLayer: AtomEncoder -> QKV -> sparse MHA (SDDMM + segment softmax + SpMM) -> out proj
// H=64, NH=8, DH=8. reshape(N, DH, NH) of row-major [N,64] => [n,d,h] = flat[n*64 + d*8 + h].
//
// Round-4: node_attn was latency-bound (VALUBusy 37%, occ 85%, hbm 21%): serial
// csr->k gather chain + 2 exp/edge. Fix: unroll edge loop x4 (4 independent
// gather chains in flight) + batched online-softmax (1.25 exp/edge). Also fuse
// degree into encode and the tsum-scan into add_base: 8 -> 6 stream ops.

#define NPB 4  // waves (nodes) per 256-thread block

// ---------------- encode: atom embedding sum + QKV projection + degree histogram ----
__global__ void encode_qkv_degree_kernel(const int* __restrict__ X,
                                         const float* __restrict__ atom_emb,
                                         const float* __restrict__ Wq, const float* __restrict__ bq,
                                         const float* __restrict__ Wk, const float* __restrict__ bk,
                                         const float* __restrict__ Wv, const float* __restrict__ bv,
                                         const int* __restrict__ row, int* __restrict__ deg,
                                         float* __restrict__ q, float* __restrict__ k,
                                         float* __restrict__ v, int N, int E)
{
    __shared__ float sWq[64 * 64];
    __shared__ float sWk[64 * 64];
    __shared__ float sWv[64 * 64];
    __shared__ float sh[NPB][64];

    const int tid = threadIdx.x;

    // degree histogram (independent of the encode work; atomics fire-and-forget)
    for (int e = blockIdx.x * 256 + tid; e < E; e += gridDim.x * 256)
        atomicAdd(&deg[row[e]], 1);

    for (int i = tid; i < 64 * 64; i += 256) {
        sWq[i] = Wq[i];
        sWk[i] = Wk[i];
        sWv[i] = Wv[i];
    }

    const int g = tid >> 6;
    const int lane = tid & 63;
    const int n = blockIdx.x * NPB + g;

    if (n < N) {
        const int offs[9] = {0, 119, 124, 136, 148, 158, 164, 170, 172};
        float hval = 0.f;
#pragma unroll
        for (int f = 0; f < 9; ++f) {
            int idx = X[n * 9 + f] + offs[f];
            hval += atom_emb[idx * 64 + lane];
        }
        sh[g][lane] = hval;  // same-wave producer/consumer; barrier below covers sW*
    }
    __syncthreads();

    if (n < N) {
        float accq = bq[lane], acck = bk[lane], accv = bv[lane];
#pragma unroll
        for (int i = 0; i < 64; ++i) {
            float hv = sh[g][i];
            accq = fmaf(hv, sWq[i * 64 + lane], accq);
            acck = fmaf(hv, sWk[i * 64 + lane], acck);
            accv = fmaf(hv, sWv[i * 64 + lane], accv);
        }
        const float scaling = 0.35355339059327373f;  // 8^-0.5
        q[n * 64 + lane] = accq * scaling;
        k[n * 64 + lane] = acck;
        v[n * 64 + lane] = accv;
    }
}

// ---------------- CSR build ----------------
// per-1024-element tile exclusive scan; tile sums out
__global__ void scan_local_kernel(const int* __restrict__ deg, int* __restrict__ offs,
                                  int* __restrict__ tsum, int N)
{
    __shared__ int lds[256];
    const int t = threadIdx.x;
    const int tbase = blockIdx.x * 1024;

    int v0[4];
    int s = 0;
#pragma unroll
    for (int i = 0; i < 4; ++i) {
        int idx = tbase + t * 4 + i;
        v0[i] = (idx < N) ? deg[idx] : 0;
        s += v0[i];
    }
    lds[t] = s;
    __syncthreads();
    for (int off = 1; off < 256; off <<= 1) {
        int x = (t >= off) ? lds[t - off] : 0;
        __syncthreads();
        lds[t] += x;
        __syncthreads();
    }
    if (t == 255) tsum[blockIdx.x] = lds[255];
    int run = (t > 0) ? lds[t - 1] : 0;
#pragma unroll
    for (int i = 0; i < 4; ++i) {
        int idx = tbase + t * 4 + i;
        if (idx < N) offs[idx] = run;
        run += v0[i];
    }
}

// add tile base (computed by redundant per-block reduction of tsum) + init cursor
__global__ void add_base_kernel(int* __restrict__ offs, const int* __restrict__ tsum,
                                int* __restrict__ cursor, int N)
{
    __shared__ int red[256];
    const int b = blockIdx.x;
    const int t = threadIdx.x;

    int s = 0;
    for (int i = t; i < b; i += 256) s += tsum[i];  // exclusive: tiles 0..b-1
    red[t] = s;
    __syncthreads();
    for (int off = 128; off > 0; off >>= 1) {
        if (t < off) red[t] += red[t + off];
        __syncthreads();
    }
    const int S = red[0];

    const int base = b * 1024;
    for (int i = t; i < 1024; i += 256) {
        int idx = base + i;
        if (idx < N) {
            int o = offs[idx] + S;
            offs[idx] = o;
            cursor[idx] = o;
        }
    }
}

__global__ void scatter_kernel(const int* __restrict__ row, const int* __restrict__ col,
                               int* __restrict__ cursor, int* __restrict__ csr_col, int E)
{
    int e = blockIdx.x * 256 + threadIdx.x;
    if (e < E) {
        int pos = atomicAdd(&cursor[row[e]], 1);
        csr_col[pos] = col[e];
    }
}

// ---------------- fused per-node attention + out-proj (online softmax, x4 unroll) ----
__global__ void node_attn_kernel(const float* __restrict__ q, const float* __restrict__ k,
                                 const float* __restrict__ v,
                                 const int* __restrict__ offs, const int* __restrict__ deg,
                                 const int* __restrict__ csr_col,
                                 const float* __restrict__ Wo, const float* __restrict__ bo,
                                 float* __restrict__ out, int N)
{
    __shared__ float sWo[64 * 64];
    __shared__ float sh[NPB][64];

    const int tid = threadIdx.x;
    for (int i = tid; i < 64 * 64; i += 256) sWo[i] = Wo[i];

    const int g = tid >> 6;
    const int lane = tid & 63;
    const int n = blockIdx.x * NPB + g;

    if (n < N) {
        const int base = offs[n];
        const int d = deg[n];
        const float qreg = q[(size_t)n * 64 + lane];

        float m = -3.4e38f;  // finite "-inf": first corr = exp(-huge) = 0, no NaN
        float sumP = 0.f;
        float acc = 0.f;

        int j = 0;
        // 4 independent gather chains in flight; batched online-softmax update
        for (; j + 3 < d; j += 4) {
            const int c0 = csr_col[base + j + 0];
            const int c1 = csr_col[base + j + 1];
            const int c2 = csr_col[base + j + 2];
            const int c3 = csr_col[base + j + 3];
            float k0 = k[(size_t)c0 * 64 + lane];
            float k1 = k[(size_t)c1 * 64 + lane];
            float k2 = k[(size_t)c2 * 64 + lane];
            float k3 = k[(size_t)c3 * 64 + lane];
            float v0 = v[(size_t)c0 * 64 + lane];
            float v1 = v[(size_t)c1 * 64 + lane];
            float v2 = v[(size_t)c2 * 64 + lane];
            float v3 = v[(size_t)c3 * 64 + lane];

            float p0 = qreg * k0, p1 = qreg * k1, p2 = qreg * k2, p3 = qreg * k3;
            p0 += __shfl_xor(p0, 8, 64);  p1 += __shfl_xor(p1, 8, 64);
            p2 += __shfl_xor(p2, 8, 64);  p3 += __shfl_xor(p3, 8, 64);
            p0 += __shfl_xor(p0, 16, 64); p1 += __shfl_xor(p1, 16, 64);
            p2 += __shfl_xor(p2, 16, 64); p3 += __shfl_xor(p3, 16, 64);
            p0 += __shfl_xor(p0, 32, 64); p1 += __shfl_xor(p1, 32, 64);
            p2 += __shfl_xor(p2, 32, 64); p3 += __shfl_xor(p3, 32, 64);

            float mb   = fmaxf(fmaxf(p0, p1), fmaxf(p2, p3));
            float mNew = fmaxf(m, mb);
            float corr = __expf(m - mNew);
            float e0 = __expf(p0 - mNew), e1 = __expf(p1 - mNew);
            float e2 = __expf(p2 - mNew), e3 = __expf(p3 - mNew);
            sumP = fmaf(sumP, corr, (e0 + e1) + (e2 + e3));
            acc  = fmaf(acc, corr, fmaf(e0, v0, fmaf(e1, v1, fmaf(e2, v2, e3 * v3))));
            m = mNew;
        }
        for (; j < d; ++j) {
            int c = csr_col[base + j];
            float prod = qreg * k[(size_t)c * 64 + lane];
            prod += __shfl_xor(prod, 8, 64);
            prod += __shfl_xor(prod, 16, 64);
            prod += __shfl_xor(prod, 32, 64);
            float mNew = fmaxf(m, prod);
            float corr = __expf(m - mNew);
            float p = __expf(prod - mNew);
            sumP = fmaf(sumP, corr, p);
            acc  = fmaf(acc, corr, p * v[(size_t)c * 64 + lane]);
            m = mNew;
        }
        sh[g][lane] = (d > 0) ? acc / sumP : 0.f;  // empty segment -> 0 -> out = bo
    }
    __syncthreads();  // covers sWo staging and sh writes

    if (n < N) {
        float o = bo[lane];
#pragma unroll
        for (int i = 0; i < 64; ++i) o = fmaf(sh[g][i], sWo[i * 64 + lane], o);
        out[n * 64 + lane] = o;
    }
}

extern "C" void kernel_launch(void* const* d_in, const int* in_sizes, int n_in,
                              void* d_out, int out_size, void* d_ws, size_t ws_size,
                              hipStream_t stream)
{
    const int*   X        = (const int*)d_in[0];
    const int*   row      = (const int*)d_in[1];
    const int*   col      = (const int*)d_in[2];
    const float* atom_emb = (const float*)d_in[3];
    const float* Wq       = (const float*)d_in[4];
    const float* bq       = (const float*)d_in[5];
    const float* Wk       = (const float*)d_in[6];
    const float* bk       = (const float*)d_in[7];
    const float* Wv       = (const float*)d_in[8];
    const float* bv       = (const float*)d_in[9];
    const float* Wo       = (const float*)d_in[10];
    const float* bo       = (const float*)d_in[11];

    const int N = in_sizes[0] / 9;
    const int E = in_sizes[1];
    const int nTiles = (N + 1023) / 1024;

    // Workspace layout: q | k | v | offs | deg | cursor | tsum | csr_col
    float* q   = (float*)d_ws;
    float* k   = q + (size_t)N * 64;
    float* v   = k + (size_t)N * 64;
    int* offs    = (int*)(v + (size_t)N * 64);       // N
    int* deg     = offs + N;                         // N
    int* cursor  = deg + N;                          // N
    int* tsum    = cursor + N;                       // nTiles (<=1024)
    int* csr_col = tsum + 1024;                      // E
    // total ~ (19.2M + 0.3M + 1.6M)*4B ~ 85 MB

    // ws is poisoned 0xAA before every timed call: zero the histogram.
    hipMemsetAsync(deg, 0, (size_t)N * sizeof(int), stream);

    encode_qkv_degree_kernel<<<(N + NPB - 1) / NPB, 256, 0, stream>>>(
        X, atom_emb, Wq, bq, Wk, bk, Wv, bv, row, deg, q, k, v, N, E);

    scan_local_kernel<<<nTiles, 256, 0, stream>>>(deg, offs, tsum, N);
    add_base_kernel<<<nTiles, 256, 0, stream>>>(offs, tsum, cursor, N);
    scatter_kernel<<<(E + 255) / 256, 256, 0, stream>>>(row, col, cursor, csr_col, E);

    node_attn_kernel<<<(N + NPB - 1) / NPB, 256, 0, stream>>>(
        q, k, v, offs, deg, csr_col, Wo, bo, (float*)d_out, N);
}

// Round 5
// 462.914 us; speedup vs baseline: 2.0725x; 1.1434x over previous
//
#include <hip/hip_runtime.h>
#include <hip/hip_bf16.h>

// GTLayer: AtomEncoder -> QKV -> sparse MHA (SDDMM + segment softmax + SpMM) -> out proj
// H=64, NH=8, DH=8. reshape(N, DH, NH) of row-major [N,64] => [n,d,h] = flat[n*64 + d*8 + h].
//
// Round-5: encode was the leader (180us) — LDS-BW bound: 48KB LDS weight reads per
// node + 50KB staging capped occupancy at 31%. Rewrite as register-tiled GEMM:
// 64 nodes/block, thread tile = 4 nodes x 12 cols (col stride 16 => coalesced
// stores + compile-time q/k/v select), weights read from global (L1-resident
// 48KB, 4-way broadcast), only h staged in LDS (16.6KB). Same trick in
// node_attn's out-proj: Wo from L1, LDS = 1KB.

#define NPB 4  // waves (nodes) per 256-thread block in node_attn

// ---------------- encode: embedding sum + QKV GEMM (64 nodes/block) + degree ----
__global__ void encode_gemm_kernel(const int* __restrict__ X,
                                   const float* __restrict__ atom_emb,
                                   const float* __restrict__ Wq, const float* __restrict__ bq,
                                   const float* __restrict__ Wk, const float* __restrict__ bk,
                                   const float* __restrict__ Wv, const float* __restrict__ bv,
                                   const int* __restrict__ row, int* __restrict__ deg,
                                   float* __restrict__ q, float* __restrict__ k,
                                   float* __restrict__ v, int N, int E)
{
    __shared__ float sH[64][65];  // [node-in-tile][dim], pad 65 => conflict-free r/w

    const int tid = threadIdx.x;

    // degree histogram (independent; atomics fire-and-forget)
    for (int e = blockIdx.x * 256 + tid; e < E; e += gridDim.x * 256)
        atomicAdd(&deg[row[e]], 1);

    // embedding phase: wave w -> nodes w*16..w*16+15, lane = dim
    const int wv = tid >> 6, lane = tid & 63;
    const int nbase = blockIdx.x * 64;
    const int offs[9] = {0, 119, 124, 136, 148, 158, 164, 170, 172};
    for (int nn = 0; nn < 16; ++nn) {
        const int nloc = wv * 16 + nn;
        const int n = nbase + nloc;
        float hval = 0.f;
        if (n < N) {
#pragma unroll
            for (int f = 0; f < 9; ++f)
                hval += atom_emb[(size_t)(X[n * 9 + f] + offs[f]) * 64 + lane];
        }
        sH[nloc][lane] = hval;  // bank (nloc+lane)%32: conflict-free
    }
    __syncthreads();

    // GEMM phase: thread tile = nodes ng*4..+3  x  cols {cg+16j, j=0..11}
    // j 0..3 -> Wq cols, 4..7 -> Wk, 8..11 -> Wv (compile-time select).
    const int ng = tid >> 4;
    const int cg = tid & 15;

    float acc[4][12];
#pragma unroll
    for (int j = 0; j < 4; ++j) {
        const float bjq = bq[16 * j + cg];
        const float bjk = bk[16 * j + cg];
        const float bjv = bv[16 * j + cg];
#pragma unroll
        for (int i = 0; i < 4; ++i) {
            acc[i][j] = bjq;
            acc[i][4 + j] = bjk;
            acc[i][8 + j] = bjv;
        }
    }

#pragma unroll 4
    for (int kk = 0; kk < 64; ++kk) {
        float w[12];
#pragma unroll
        for (int j = 0; j < 4; ++j) {
            w[j]     = Wq[kk * 64 + 16 * j + cg];  // L1-resident, 4-way lane broadcast
            w[4 + j] = Wk[kk * 64 + 16 * j + cg];
            w[8 + j] = Wv[kk * 64 + 16 * j + cg];
        }
        const float h0 = sH[ng * 4 + 0][kk];
        const float h1 = sH[ng * 4 + 1][kk];
        const float h2 = sH[ng * 4 + 2][kk];
        const float h3 = sH[ng * 4 + 3][kk];
#pragma unroll
        for (int j = 0; j < 12; ++j) {
            acc[0][j] = fmaf(h0, w[j], acc[0][j]);
            acc[1][j] = fmaf(h1, w[j], acc[1][j]);
            acc[2][j] = fmaf(h2, w[j], acc[2][j]);
            acc[3][j] = fmaf(h3, w[j], acc[3][j]);
        }
    }

    const float scaling = 0.35355339059327373f;  // 8^-0.5, applied after bias (ref order)
#pragma unroll
    for (int i = 0; i < 4; ++i) {
        const int n = nbase + ng * 4 + i;
        if (n < N) {
#pragma unroll
            for (int j = 0; j < 4; ++j) {
                q[(size_t)n * 64 + 16 * j + cg] = acc[i][j] * scaling;
                k[(size_t)n * 64 + 16 * j + cg] = acc[i][4 + j];
                v[(size_t)n * 64 + 16 * j + cg] = acc[i][8 + j];
            }
        }
    }
}

// ---------------- CSR build ----------------
// per-1024-element tile exclusive scan; tile sums out
__global__ void scan_local_kernel(const int* __restrict__ deg, int* __restrict__ offs,
                                  int* __restrict__ tsum, int N)
{
    __shared__ int lds[256];
    const int t = threadIdx.x;
    const int tbase = blockIdx.x * 1024;

    int v0[4];
    int s = 0;
#pragma unroll
    for (int i = 0; i < 4; ++i) {
        int idx = tbase + t * 4 + i;
        v0[i] = (idx < N) ? deg[idx] : 0;
        s += v0[i];
    }
    lds[t] = s;
    __syncthreads();
    for (int off = 1; off < 256; off <<= 1) {
        int x = (t >= off) ? lds[t - off] : 0;
        __syncthreads();
        lds[t] += x;
        __syncthreads();
    }
    if (t == 255) tsum[blockIdx.x] = lds[255];
    int run = (t > 0) ? lds[t - 1] : 0;
#pragma unroll
    for (int i = 0; i < 4; ++i) {
        int idx = tbase + t * 4 + i;
        if (idx < N) offs[idx] = run;
        run += v0[i];
    }
}

// add tile base (redundant per-block reduction of tsum) + init cursor
__global__ void add_base_kernel(int* __restrict__ offs, const int* __restrict__ tsum,
                                int* __restrict__ cursor, int N)
{
    __shared__ int red[256];
    const int b = blockIdx.x;
    const int t = threadIdx.x;

    int s = 0;
    for (int i = t; i < b; i += 256) s += tsum[i];  // exclusive: tiles 0..b-1
    red[t] = s;
    __syncthreads();
    for (int off = 128; off > 0; off >>= 1) {
        if (t < off) red[t] += red[t + off];
        __syncthreads();
    }
    const int S = red[0];

    const int base = b * 1024;
    for (int i = t; i < 1024; i += 256) {
        int idx = base + i;
        if (idx < N) {
            int o = offs[idx] + S;
            offs[idx] = o;
            cursor[idx] = o;
        }
    }
}

__global__ void scatter_kernel(const int* __restrict__ row, const int* __restrict__ col,
                               int* __restrict__ cursor, int* __restrict__ csr_col, int E)
{
    int e = blockIdx.x * 256 + threadIdx.x;
    if (e < E) {
        int pos = atomicAdd(&cursor[row[e]], 1);
        csr_col[pos] = col[e];
    }
}

// ---------------- fused per-node attention + out-proj (online softmax, x4 unroll) ----
__global__ void node_attn_kernel(const float* __restrict__ q, const float* __restrict__ k,
                                 const float* __restrict__ v,
                                 const int* __restrict__ offs, const int* __restrict__ deg,
                                 const int* __restrict__ csr_col,
                                 const float* __restrict__ Wo, const float* __restrict__ bo,
                                 float* __restrict__ out, int N)
{
    __shared__ float sh[NPB][64];

    const int tid = threadIdx.x;
    const int g = tid >> 6;
    const int lane = tid & 63;
    const int n = blockIdx.x * NPB + g;

    if (n < N) {
        const int base = offs[n];
        const int d = deg[n];
        const float qreg = q[(size_t)n * 64 + lane];

        float m = -3.4e38f;  // finite "-inf": first corr = exp(-huge) = 0, no NaN
        float sumP = 0.f;
        float acc = 0.f;

        int j = 0;
        // 4 independent gather chains in flight; batched online-softmax update
        for (; j + 3 < d; j += 4) {
            const int c0 = csr_col[base + j + 0];
            const int c1 = csr_col[base + j + 1];
            const int c2 = csr_col[base + j + 2];
            const int c3 = csr_col[base + j + 3];
            float k0 = k[(size_t)c0 * 64 + lane];
            float k1 = k[(size_t)c1 * 64 + lane];
            float k2 = k[(size_t)c2 * 64 + lane];
            float k3 = k[(size_t)c3 * 64 + lane];
            float v0 = v[(size_t)c0 * 64 + lane];
            float v1 = v[(size_t)c1 * 64 + lane];
            float v2 = v[(size_t)c2 * 64 + lane];
            float v3 = v[(size_t)c3 * 64 + lane];

            float p0 = qreg * k0, p1 = qreg * k1, p2 = qreg * k2, p3 = qreg * k3;
            p0 += __shfl_xor(p0, 8, 64);  p1 += __shfl_xor(p1, 8, 64);
            p2 += __shfl_xor(p2, 8, 64);  p3 += __shfl_xor(p3, 8, 64);
            p0 += __shfl_xor(p0, 16, 64); p1 += __shfl_xor(p1, 16, 64);
            p2 += __shfl_xor(p2, 16, 64); p3 += __shfl_xor(p3, 16, 64);
            p0 += __shfl_xor(p0, 32, 64); p1 += __shfl_xor(p1, 32, 64);
            p2 += __shfl_xor(p2, 32, 64); p3 += __shfl_xor(p3, 32, 64);

            float mb   = fmaxf(fmaxf(p0, p1), fmaxf(p2, p3));
            float mNew = fmaxf(m, mb);
            float corr = __expf(m - mNew);
            float e0 = __expf(p0 - mNew), e1 = __expf(p1 - mNew);
            float e2 = __expf(p2 - mNew), e3 = __expf(p3 - mNew);
            sumP = fmaf(sumP, corr, (e0 + e1) + (e2 + e3));
            acc  = fmaf(acc, corr, fmaf(e0, v0, fmaf(e1, v1, fmaf(e2, v2, e3 * v3))));
            m = mNew;
        }
        for (; j < d; ++j) {
            int c = csr_col[base + j];
            float prod = qreg * k[(size_t)c * 64 + lane];
            prod += __shfl_xor(prod, 8, 64);
            prod += __shfl_xor(prod, 16, 64);
            prod += __shfl_xor(prod, 32, 64);
            float mNew = fmaxf(m, prod);
            float corr = __expf(m - mNew);
            float p = __expf(prod - mNew);
            sumP = fmaf(sumP, corr, p);
            acc  = fmaf(acc, corr, p * v[(size_t)c * 64 + lane]);
            m = mNew;
        }
        sh[g][lane] = (d > 0) ? acc / sumP : 0.f;  // empty segment -> 0 -> out = bo
    }
    __syncthreads();  // sh visibility (cheap; 4 waves)

    if (n < N) {
        float o = bo[lane];
#pragma unroll
        for (int i = 0; i < 64; ++i)
            o = fmaf(sh[g][i], Wo[i * 64 + lane], o);  // Wo: 16KB, L1-resident broadcast lines
        out[(size_t)n * 64 + lane] = o;
    }
}

extern "C" void kernel_launch(void* const* d_in, const int* in_sizes, int n_in,
                              void* d_out, int out_size, void* d_ws, size_t ws_size,
                              hipStream_t stream)
{
    const int*   X        = (const int*)d_in[0];
    const int*   row      = (const int*)d_in[1];
    const int*   col      = (const int*)d_in[2];
    const float* atom_emb = (const float*)d_in[3];
    const float* Wq       = (const float*)d_in[4];
    const float* bq       = (const float*)d_in[5];
    const float* Wk       = (const float*)d_in[6];
    const float* bk       = (const float*)d_in[7];
    const float* Wv       = (const float*)d_in[8];
    const float* bv       = (const float*)d_in[9];
    const float* Wo       = (const float*)d_in[10];
    const float* bo       = (const float*)d_in[11];

    const int N = in_sizes[0] / 9;
    const int E = in_sizes[1];
    const int nTiles = (N + 1023) / 1024;

    // Workspace layout: q | k | v | offs | deg | cursor | tsum | csr_col
    float* q   = (float*)d_ws;
    float* k   = q + (size_t)N * 64;
    float* v   = k + (size_t)N * 64;
    int* offs    = (int*)(v + (size_t)N * 64);       // N
    int* deg     = offs + N;                         // N
    int* cursor  = deg + N;                          // N
    int* tsum    = cursor + N;                       // nTiles (<=1024)
    int* csr_col = tsum + 1024;                      // E
    // total ~ (19.2M + 0.3M + 1.6M)*4B ~ 85 MB

    // ws is poisoned 0xAA before every timed call: zero the histogram.
    hipMemsetAsync(deg, 0, (size_t)N * sizeof(int), stream);

    encode_gemm_kernel<<<(N + 63) / 64, 256, 0, stream>>>(
        X, atom_emb, Wq, bq, Wk, bk, Wv, bv, row, deg, q, k, v, N, E);

    scan_local_kernel<<<nTiles, 256, 0, stream>>>(deg, offs, tsum, N);
    add_base_kernel<<<nTiles, 256, 0, stream>>>(offs, tsum, cursor, N);
    scatter_kernel<<<(E + 255) / 256, 256, 0, stream>>>(row, col, cursor, csr_col, E);

    node_attn_kernel<<<(N + NPB - 1) / NPB, 256, 0, stream>>>(
        q, k, v, offs, deg, csr_col, Wo, bo, (float*)d_out, N);
}